// Round 7
// baseline (70.627 us; speedup 1.0000x reference)
//
#include <hip/hip_runtime.h>

#define NEG_SLOPE 0.2f
#define EPS 1e-6f

// x: [B=4, C=64, V=3, N=32768] f32, W: [64,64] f32, out like x
// d[o,v,n] = sum_i W[o,i]*x[i,v,n]; out = dot>=0 ? x : x - 0.8*(dot/(dnsq+eps))*d
// Operand-swapped bf16 MFMA: E[n,o] = x^T W^T so each lane holds 4 consecutive
// n per o -> float4 epilogue loads/stores. hi/lo 3-product split for accuracy.

#define C_CH 64
#define V_DIM 3
#define N_FULL 32768
#define NT 32
#define THREADS 256

typedef __attribute__((ext_vector_type(8))) short bf16x8;
typedef __attribute__((ext_vector_type(4))) float f32x4;

__device__ __forceinline__ ushort f2bf(float f) {
    union { float f; unsigned u; } v; v.f = f;
    unsigned r = v.u + 0x7FFFu + ((v.u >> 16) & 1u);  // RNE
    return (ushort)(r >> 16);
}
__device__ __forceinline__ float bf2f(ushort s) {
    union { unsigned u; float f; } v; v.u = ((unsigned)s) << 16; return v.f;
}
// pack f32 -> (hi bf16 | lo bf16) in 4 VALU: round-half-up hi, truncated lo
__device__ __forceinline__ unsigned pack_hl(float x) {
    union { float f; unsigned u; } a; a.f = x;
    unsigned t0 = a.u + 0x8000u;
    union { unsigned u; float f; } hb; hb.u = t0 & 0xffff0000u;
    union { float f; unsigned u; } rb; rb.f = x - hb.f;
    return __builtin_amdgcn_perm(t0, rb.u, 0x07060302u);  // [t0.b3,t0.b2,rb.b3,rb.b2]
}
__device__ __forceinline__ float u2f(unsigned u) {
    union { unsigned u; float f; } v; v.u = u; return v.f;
}

// ---- pre-kernel: split W fp32 -> Whi/Wlo bf16 (8 KB each), RNE both
__global__ void w_split_kernel(const float* __restrict__ W,
                               ushort* __restrict__ whi, ushort* __restrict__ wlo) {
    int i = blockIdx.x * 256 + threadIdx.x;
    if (i < C_CH * C_CH) {
        float w = W[i];
        ushort h = f2bf(w);
        whi[i] = h;
        wlo[i] = f2bf(w - bf2f(h));
    }
}

// swizzle (dword units, bits 2-4): spreads rows across bank groups;
// involution (XOR), 4-dword aligned -> uint4 ops stay 16B-aligned
__device__ __forceinline__ int swz(int row) {
    return ((row & 7) << 2) ^ (((row >> 3) & 1) << 4);
}

template<bool USE_WS>
__global__ __launch_bounds__(THREADS, 6)
void vn_mfma32(const float* __restrict__ x,
               const float* __restrict__ Wf,
               const ushort* __restrict__ whi, const ushort* __restrict__ wlo,
               float* __restrict__ out) {
    // LDS row = v*64 + i, packed (hi<<16)|lo. 24 KB.
    __shared__ unsigned xs[V_DIM * C_CH][NT];

    const int t    = threadIdx.x;
    const int tile = blockIdx.x;
    const int b    = tile >> 10;            // 1024 tiles per batch
    const int n0   = (tile & 1023) << 5;    // *32

    const float* xb = x + (size_t)b * (C_CH * V_DIM * N_FULL) + n0;

    const int lane = t & 63;
    const int w    = t >> 6;
    const int wo   = w >> 1;   // o-half -> 32 channels
    const int wn   = w & 1;    // n-half -> 16 cols
    const int l4   = lane & 15;
    const int hi   = lane >> 4;

    // ---- B fragments (W, row-major): col=o=l4, k=i=kh*32+hi*8+j
    bf16x8 Bh[2][2], Bl[2][2];
    if (USE_WS) {
        #pragma unroll
        for (int m = 0; m < 2; ++m)
            #pragma unroll
            for (int kh = 0; kh < 2; ++kh) {
                size_t off = (size_t)(wo * 32 + m * 16 + l4) * C_CH + kh * 32 + hi * 8;
                Bh[m][kh] = *(const bf16x8*)(whi + off);
                Bl[m][kh] = *(const bf16x8*)(wlo + off);
            }
    } else {
        #pragma unroll
        for (int m = 0; m < 2; ++m)
            #pragma unroll
            for (int kh = 0; kh < 2; ++kh) {
                const float* wp = Wf + (size_t)(wo * 32 + m * 16 + l4) * C_CH + kh * 32 + hi * 8;
                float4 wa = *(const float4*)wp;
                float4 wb = *(const float4*)(wp + 4);
                float wf[8] = {wa.x, wa.y, wa.z, wa.w, wb.x, wb.y, wb.z, wb.w};
                bf16x8 h, l;
                #pragma unroll
                for (int j = 0; j < 8; ++j) {
                    ushort hb = f2bf(wf[j]);
                    h[j] = (short)hb;
                    l[j] = (short)f2bf(wf[j] - bf2f(hb));
                }
                Bh[m][kh] = h; Bl[m][kh] = l;
            }
    }

    // ---- stage x tile: 192 global rows x 32 f32 -> packed LDS [v*64+i][n]
    #pragma unroll
    for (int it = 0; it < 6; ++it) {
        int idx = t + it * THREADS;      // 0..1535 float4-slots
        int r   = idx >> 3;              // global row 0..191 (8 float4/row)
        int c4  = (idx & 7) << 2;        // dword col base
        int i   = (r * 171) >> 9;        // r / 3 (exact for r < 768)
        int v   = r - 3 * i;
        int rowp = v * 64 + i;
        float4 vf4 = *(const float4*)(xb + (size_t)r * N_FULL + c4);
        float vf[4] = {vf4.x, vf4.y, vf4.z, vf4.w};
        unsigned p[4];
        #pragma unroll
        for (int q = 0; q < 4; ++q) p[q] = pack_hl(vf[q]);
        *(uint4*)&xs[rowp][c4 ^ swz(rowp)] = *(const uint4*)p;
    }
    __syncthreads();

    f32x4 acc[2][3];
    #pragma unroll
    for (int m = 0; m < 2; ++m)
        #pragma unroll
        for (int v = 0; v < 3; ++v)
            acc[m][v] = (f32x4){0.f, 0.f, 0.f, 0.f};

    // ---- MFMA: A-frag = x (row=n=l4, k=i), built from packed LDS
    const int acolb = (wn * 16 + l4) ^ ((hi & 1) << 4);  // ^ (j<<2) per element
    #pragma unroll
    for (int v = 0; v < 3; ++v) {
        #pragma unroll
        for (int kh = 0; kh < 2; ++kh) {
            const int rowb = v * 64 + kh * 32 + hi * 8;
            unsigned p[8];
            #pragma unroll
            for (int j = 0; j < 8; ++j)
                p[j] = xs[rowb + j][acolb ^ (j << 2)];
            union { bf16x8 v8; unsigned d[4]; } AH, AL;
            #pragma unroll
            for (int q = 0; q < 4; ++q) {
                AH.d[q] = __builtin_amdgcn_perm(p[2 * q + 1], p[2 * q], 0x07060302u);
                AL.d[q] = __builtin_amdgcn_perm(p[2 * q + 1], p[2 * q], 0x05040100u);
            }
            #pragma unroll
            for (int m = 0; m < 2; ++m) {
                acc[m][v] = __builtin_amdgcn_mfma_f32_16x16x32_bf16(AH.v8, Bh[m][kh], acc[m][v], 0, 0, 0);
                acc[m][v] = __builtin_amdgcn_mfma_f32_16x16x32_bf16(AL.v8, Bh[m][kh], acc[m][v], 0, 0, 0);
                acc[m][v] = __builtin_amdgcn_mfma_f32_16x16x32_bf16(AH.v8, Bl[m][kh], acc[m][v], 0, 0, 0);
            }
        }
    }

    // ---- epilogue: lane holds d[o = wo*32+m*16+l4][n = wn*16+hi*4+r], r=0..3
    const int ncol = wn * 16 + hi * 4;                    // dword col of our 4 n's
    const int ecol = ncol ^ ((l4 & 7) << 2) ^ (((l4 >> 3) & 1) << 4);
    #pragma unroll
    for (int m = 0; m < 2; ++m) {
        const int o = wo * 32 + m * 16 + l4;
        float xv[3][4];
        #pragma unroll
        for (int v = 0; v < 3; ++v) {
            uint4 p4 = *(const uint4*)&xs[v * 64 + o][ecol];
            unsigned pw[4] = {p4.x, p4.y, p4.z, p4.w};
            #pragma unroll
            for (int q = 0; q < 4; ++q)
                xv[v][q] = u2f(pw[q] & 0xffff0000u) + u2f(pw[q] << 16);
        }
        float fm[4];
        #pragma unroll
        for (int r = 0; r < 4; ++r) {
            float d0 = acc[m][0][r], d1 = acc[m][1][r], d2 = acc[m][2][r];
            float dot  = xv[0][r] * d0 + xv[1][r] * d1 + xv[2][r] * d2;
            float dnsq = d0 * d0 + d1 * d1 + d2 * d2;
            float f = (1.0f - NEG_SLOPE) * dot * __builtin_amdgcn_rcpf(dnsq + EPS);
            fm[r] = (dot >= 0.f) ? 0.f : f;
        }
        float* ob = out + (size_t)b * (C_CH * V_DIM * N_FULL)
                        + (size_t)o * (V_DIM * N_FULL) + n0 + ncol;
        #pragma unroll
        for (int v = 0; v < 3; ++v) {
            float4 o4;
            o4.x = fmaf(-fm[0], acc[m][v][0], xv[v][0]);
            o4.y = fmaf(-fm[1], acc[m][v][1], xv[v][1]);
            o4.z = fmaf(-fm[2], acc[m][v][2], xv[v][2]);
            o4.w = fmaf(-fm[3], acc[m][v][3], xv[v][3]);
            *(float4*)(ob + (size_t)v * N_FULL) = o4;
        }
    }
}

extern "C" void kernel_launch(void* const* d_in, const int* in_sizes, int n_in,
                              void* d_out, int out_size, void* d_ws, size_t ws_size,
                              hipStream_t stream) {
    const float* x = (const float*)d_in[0];
    const float* W = (const float*)d_in[1];
    float* out = (float*)d_out;

    const int B = 4;
    const int blocks = B * (N_FULL / NT);  // 4096

    if (ws_size >= 2u * C_CH * C_CH * sizeof(ushort)) {
        ushort* whi = (ushort*)d_ws;
        ushort* wlo = whi + C_CH * C_CH;
        w_split_kernel<<<(C_CH * C_CH + 255) / 256, 256, 0, stream>>>(W, whi, wlo);
        vn_mfma32<true><<<blocks, THREADS, 0, stream>>>(x, W, whi, wlo, out);
    } else {
        vn_mfma32<false><<<blocks, THREADS, 0, stream>>>(x, W, nullptr, nullptr, out);
    }
}

// Round 8
// 43.599 us; speedup vs baseline: 1.6199x; 1.6199x over previous
//
#include <hip/hip_runtime.h>

#define NEG_SLOPE 0.2f
#define EPS 1e-6f

// x: [B=4, C=64, V=3, N=32768] f32, W: [64,64] f32, out like x
// d[o,v,n] = sum_i W[o,i]*x[i,v,n]; out = dot>=0 ? x : x - 0.8*(dot/(dnsq+eps))*d
// bf16 MFMA (A=W frag, B=x frag), hi/lo 3-product split.
// 512-thread blocks, NT=64, 48KB LDS -> 3 blocks/CU (24 waves, 75% ceiling).
// swizzle col ^= ((row>>3)&3)<<4 keeps every LDS op <=2-way (free).

#define C_CH 64
#define V_DIM 3
#define N_FULL 32768
#define NT 64
#define THREADS 512

typedef __attribute__((ext_vector_type(8))) short bf16x8;
typedef __attribute__((ext_vector_type(4))) float f32x4;

__device__ __forceinline__ ushort f2bf(float f) {
    union { float f; unsigned u; } v; v.f = f;
    unsigned r = v.u + 0x7FFFu + ((v.u >> 16) & 1u);  // RNE
    return (ushort)(r >> 16);
}
__device__ __forceinline__ float bf2f(ushort s) {
    union { unsigned u; float f; } v; v.u = ((unsigned)s) << 16; return v.f;
}
// pack f32 -> (hi bf16 | lo bf16) in 4 VALU: round-half-up hi, truncated lo
__device__ __forceinline__ unsigned pack_hl(float x) {
    union { float f; unsigned u; } a; a.f = x;
    unsigned t0 = a.u + 0x8000u;
    union { unsigned u; float f; } hb; hb.u = t0 & 0xffff0000u;
    union { float f; unsigned u; } rb; rb.f = x - hb.f;
    return __builtin_amdgcn_perm(t0, rb.u, 0x07060302u);  // [t0.b3,t0.b2,rb.b3,rb.b2]
}
__device__ __forceinline__ float u2f(unsigned u) {
    union { unsigned u; float f; } v; v.u = u; return v.f;
}

// ---- pre-kernel: split W fp32 -> Whi/Wlo bf16 (8 KB each), RNE both
__global__ void w_split_kernel(const float* __restrict__ W,
                               ushort* __restrict__ whi, ushort* __restrict__ wlo) {
    int i = blockIdx.x * 256 + threadIdx.x;
    if (i < C_CH * C_CH) {
        float w = W[i];
        ushort h = f2bf(w);
        whi[i] = h;
        wlo[i] = f2bf(w - bf2f(h));
    }
}

// dword-col swizzle: XOR col bits 4-5 with row bits 3-4 -> all accesses <=2-way
__device__ __forceinline__ int swz(int row) { return ((row >> 3) & 3) << 4; }

template<bool USE_WS>
__global__ __launch_bounds__(THREADS, 6)
void vn_mfma64(const float* __restrict__ x,
               const float* __restrict__ Wf,
               const ushort* __restrict__ whi, const ushort* __restrict__ wlo,
               float* __restrict__ out) {
    // LDS row = v*64 + i, packed (hi<<16)|lo. 48 KB.
    __shared__ unsigned xs[V_DIM * C_CH][NT];

    const int t    = threadIdx.x;
    const int tile = blockIdx.x;
    const int b    = tile >> 9;            // 512 tiles per batch
    const int n0   = (tile & 511) << 6;    // *64

    const float* xb = x + (size_t)b * (C_CH * V_DIM * N_FULL) + n0;

    const int lane = t & 63;
    const int w    = t >> 6;   // 0..7
    const int wo   = w >> 2;   // o-half -> 32 channels
    const int wn   = w & 3;    // n-quarter -> 16 cols
    const int l4   = lane & 15;
    const int hi   = lane >> 4;

    // ---- A fragments (W): row o = wo*32+m*16+l4, k = kh*32+hi*8+j
    bf16x8 Ah[2][2], Al[2][2];
    if (USE_WS) {
        #pragma unroll
        for (int m = 0; m < 2; ++m)
            #pragma unroll
            for (int kh = 0; kh < 2; ++kh) {
                size_t off = (size_t)(wo * 32 + m * 16 + l4) * C_CH + kh * 32 + hi * 8;
                Ah[m][kh] = *(const bf16x8*)(whi + off);
                Al[m][kh] = *(const bf16x8*)(wlo + off);
            }
    } else {
        #pragma unroll
        for (int m = 0; m < 2; ++m)
            #pragma unroll
            for (int kh = 0; kh < 2; ++kh) {
                const float* wp = Wf + (size_t)(wo * 32 + m * 16 + l4) * C_CH + kh * 32 + hi * 8;
                float4 wa = *(const float4*)wp;
                float4 wb = *(const float4*)(wp + 4);
                float wf[8] = {wa.x, wa.y, wa.z, wa.w, wb.x, wb.y, wb.z, wb.w};
                bf16x8 h, l;
                #pragma unroll
                for (int j = 0; j < 8; ++j) {
                    ushort hb = f2bf(wf[j]);
                    h[j] = (short)hb;
                    l[j] = (short)f2bf(wf[j] - bf2f(hb));
                }
                Ah[m][kh] = h; Al[m][kh] = l;
            }
    }

    // ---- stage x tile: 192 global rows x 64 f32 -> packed LDS [v*64+i][n]
    // global row r = 3*i + v ; LDS row = v*64 + i ; 16 float4 per row
    #pragma unroll
    for (int it = 0; it < 6; ++it) {
        int idx = t + it * THREADS;      // 0..3071 float4-slots
        int r   = idx >> 4;              // global row 0..191
        int c4  = (idx & 15) << 2;       // dword col base
        int i   = (r * 171) >> 9;        // r / 3 (exact for r < 768)
        int v   = r - 3 * i;
        int rowp = v * 64 + i;
        float4 vf4 = *(const float4*)(xb + (size_t)r * N_FULL + c4);
        float vf[4] = {vf4.x, vf4.y, vf4.z, vf4.w};
        unsigned p[4];
        #pragma unroll
        for (int q = 0; q < 4; ++q) p[q] = pack_hl(vf[q]);
        *(uint4*)&xs[rowp][c4 ^ swz(rowp)] = *(const uint4*)p;
    }
    __syncthreads();

    f32x4 acc[2][3];
    #pragma unroll
    for (int m = 0; m < 2; ++m)
        #pragma unroll
        for (int v = 0; v < 3; ++v)
            acc[m][v] = (f32x4){0.f, 0.f, 0.f, 0.f};

    // ---- MFMA: B-frag (x) rows = v*64+kh*32+hi*8+j -> (row>>3)&3 == hi
    const int acol = (wn * 16 + l4) ^ (hi << 4);  // const per thread
    #pragma unroll
    for (int v = 0; v < 3; ++v) {
        #pragma unroll
        for (int kh = 0; kh < 2; ++kh) {
            const int rowb = v * 64 + kh * 32 + hi * 8;
            unsigned p[8];
            #pragma unroll
            for (int j = 0; j < 8; ++j)
                p[j] = xs[rowb + j][acol];
            union { bf16x8 v8; unsigned d[4]; } BH, BL;
            #pragma unroll
            for (int q = 0; q < 4; ++q) {
                BH.d[q] = __builtin_amdgcn_perm(p[2 * q + 1], p[2 * q], 0x07060302u);
                BL.d[q] = __builtin_amdgcn_perm(p[2 * q + 1], p[2 * q], 0x05040100u);
            }
            #pragma unroll
            for (int m = 0; m < 2; ++m) {
                acc[m][v] = __builtin_amdgcn_mfma_f32_16x16x32_bf16(Ah[m][kh], BH.v8, acc[m][v], 0, 0, 0);
                acc[m][v] = __builtin_amdgcn_mfma_f32_16x16x32_bf16(Ah[m][kh], BL.v8, acc[m][v], 0, 0, 0);
                acc[m][v] = __builtin_amdgcn_mfma_f32_16x16x32_bf16(Al[m][kh], BH.v8, acc[m][v], 0, 0, 0);
            }
        }
    }

    // ---- epilogue: C/D col=l4 (n), row=hi*4+r (o within 16); coalesced stores
    const int n = wn * 16 + l4;
    float* ob = out + (size_t)b * (C_CH * V_DIM * N_FULL) + n0 + n;
    #pragma unroll
    for (int m = 0; m < 2; ++m) {
        #pragma unroll
        for (int r = 0; r < 4; ++r) {
            const int o = wo * 32 + m * 16 + hi * 4 + r;
            // row = v*64+o -> (row>>3)&3 = (m*2 + (hi>>1)) & 3
            const int ecol = n ^ (((m * 2 + (hi >> 1)) & 3) << 4);
            float xv[3], dv[3];
            #pragma unroll
            for (int v = 0; v < 3; ++v) {
                unsigned p = xs[v * 64 + o][ecol];
                xv[v] = u2f(p & 0xffff0000u) + u2f(p << 16);
                dv[v] = acc[m][v][r];
            }
            float dot  = xv[0] * dv[0] + xv[1] * dv[1] + xv[2] * dv[2];
            float dnsq = dv[0] * dv[0] + dv[1] * dv[1] + dv[2] * dv[2];
            float f = (1.0f - NEG_SLOPE) * dot * __builtin_amdgcn_rcpf(dnsq + EPS);
            f = (dot >= 0.f) ? 0.f : f;
            float o0 = fmaf(-f, dv[0], xv[0]);
            float o1 = fmaf(-f, dv[1], xv[1]);
            float o2 = fmaf(-f, dv[2], xv[2]);
            float* op = ob + (size_t)o * (V_DIM * N_FULL);
            op[0 * N_FULL] = o0;
            op[1 * N_FULL] = o1;
            op[2 * N_FULL] = o2;
        }
    }
}

extern "C" void kernel_launch(void* const* d_in, const int* in_sizes, int n_in,
                              void* d_out, int out_size, void* d_ws, size_t ws_size,
                              hipStream_t stream) {
    const float* x = (const float*)d_in[0];
    const float* W = (const float*)d_in[1];
    float* out = (float*)d_out;

    const int B = 4;
    const int blocks = B * (N_FULL / NT);  // 2048

    if (ws_size >= 2u * C_CH * C_CH * sizeof(ushort)) {
        ushort* whi = (ushort*)d_ws;
        ushort* wlo = whi + C_CH * C_CH;
        w_split_kernel<<<(C_CH * C_CH + 255) / 256, 256, 0, stream>>>(W, whi, wlo);
        vn_mfma64<true><<<blocks, THREADS, 0, stream>>>(x, W, whi, wlo, out);
    } else {
        vn_mfma64<false><<<blocks, THREADS, 0, stream>>>(x, W, nullptr, nullptr, out);
    }
}